// Round 4
// baseline (5021.165 us; speedup 1.0000x reference)
//
#include <hip/hip_runtime.h>
#include <hip/hip_fp16.h>
#include <cstdint>
#include <cstddef>

// Problem constants (T, B, V, HID, L) from the reference.
#define TT 1024
#define BB 64
#define VV 256
#define HH 512
static const size_t TBH = (size_t)TT * BB * HH;   // 33,554,432 floats

typedef _Float16 half2v __attribute__((ext_vector_type(2)));
union U32H2 { unsigned u; half2v h; };

__device__ __forceinline__ unsigned pack_f16x2(float a, float b) {
    __half ha = __float2half_rn(a);
    __half hb = __float2half_rn(b);
    return (unsigned)__half_as_ushort(ha) | ((unsigned)__half_as_ushort(hb) << 16);
}

__device__ __forceinline__ float tanh_fast(float x) {
    float ax = fabsf(x);
    float e = __expf(-2.0f * ax);
    float r = (1.0f - e) * __builtin_amdgcn_rcpf(1.0f + e);
    return copysignf(r, x);
}

__device__ __forceinline__ float fdot2(unsigned w, unsigned h, float acc) {
    U32H2 uw; uw.u = w;
    U32H2 uh; uh.u = h;
#if __has_builtin(__builtin_amdgcn_fdot2)
    return __builtin_amdgcn_fdot2(uw.h, uh.h, acc, false);
#else
    return acc + (float)uw.h[0] * (float)uh.h[0] + (float)uw.h[1] * (float)uh.h[1];
#endif
}

// ---------------------------------------------------------------------------
// Weight prep:
//  Wq0/Wq1 : recurrent Wh rows as f16x2 k-pairs   [512 rows][256 pairs]
//  Wp0/Wp1 : input-proj Wx^T as f16x2 k-pairs     [K/2 pairs][512 cols]
// ---------------------------------------------------------------------------
__global__ void pack_weights(const float* __restrict__ Wnet,
                             const float* __restrict__ Wdeep,
                             unsigned* __restrict__ Wq0, unsigned* __restrict__ Wq1,
                             unsigned* __restrict__ Wp0, unsigned* __restrict__ Wp1) {
    int id = blockIdx.x * 256 + threadIdx.x;
    const int NQ  = HH * (HH / 2);     // 131072
    const int NP0 = (VV / 2) * HH;     // 65536
    const int NP1 = (HH / 2) * HH;     // 131072
    if (id < NQ) {
        int i = id >> 8, jp = id & 255;
        const float* row = Wnet + (size_t)i * (VV + HH) + VV;   // Wh0[i][:]
        Wq0[id] = pack_f16x2(row[2 * jp], row[2 * jp + 1]);
        return;
    }
    id -= NQ;
    if (id < NQ) {
        int i = id >> 8, jp = id & 255;
        const float* row = Wdeep + (size_t)i * (2 * HH) + HH;   // Wh1[i][:]
        Wq1[id] = pack_f16x2(row[2 * jp], row[2 * jp + 1]);
        return;
    }
    id -= NQ;
    if (id < NP0) {
        int k2 = id >> 9, n = id & 511;
        const float* row = Wnet + (size_t)n * (VV + HH);
        Wp0[id] = pack_f16x2(row[2 * k2], row[2 * k2 + 1]);
        return;
    }
    id -= NP0;
    if (id < NP1) {
        int k2 = id >> 9, n = id & 511;
        const float* row = Wdeep + (size_t)n * (2 * HH);
        Wp1[id] = pack_f16x2(row[2 * k2], row[2 * k2 + 1]);
        return;
    }
}

// ---------------------------------------------------------------------------
// Input-projection GEMM (f16 dot2): C[M,512] = A[M,K] @ Wx^T + bias.
// 32-row tile staged as f16 pairs in LDS (fully before any C write -> in-place
// safe for A == C).  W staged in LDS chunks of 16 k-pairs (amortizes L2/L1
// port pressure).  Block: 256 thr; thread: 8 rows x 8 cols (two col-quads
// n0 and n0+256).  LDS: As2 + Wtile <= 64 KB.
// ---------------------------------------------------------------------------
__device__ __forceinline__ void dot8(float* acc, unsigned a, uint4 w0, uint4 w1) {
    acc[0] = fdot2(w0.x, a, acc[0]);
    acc[1] = fdot2(w0.y, a, acc[1]);
    acc[2] = fdot2(w0.z, a, acc[2]);
    acc[3] = fdot2(w0.w, a, acc[3]);
    acc[4] = fdot2(w1.x, a, acc[4]);
    acc[5] = fdot2(w1.y, a, acc[5]);
    acc[6] = fdot2(w1.z, a, acc[6]);
    acc[7] = fdot2(w1.w, a, acc[7]);
}

__launch_bounds__(256, 2)
__global__ void xproj_f16(const float* __restrict__ A,
                          const unsigned* __restrict__ Wp,   // [K2][512] f16x2
                          const float* __restrict__ bias,
                          float* __restrict__ C, int K2) {
    extern __shared__ unsigned lds[];      // As2[32][K2] then Wtile[16][512]
    unsigned* As2 = lds;
    unsigned* Wt  = lds + 32 * K2;
    const int m0 = blockIdx.x * 32;
    const int t = threadIdx.x;

    // stage + convert A tile (32 rows x 2*K2 floats), coalesced float4 reads
    const int nf4 = 16 * K2;               // 32*2*K2/4
    const float4* Ag = (const float4*)(A + (size_t)m0 * (2 * K2));
    for (int idx = t; idx < nf4; idx += 256) {
        float4 v = Ag[idx];
        As2[idx * 2]     = pack_f16x2(v.x, v.y);
        As2[idx * 2 + 1] = pack_f16x2(v.z, v.w);
    }

    const int c  = t & 63;                 // col group
    const int rg = t >> 6;                 // 0..3 -> rows rg*8..rg*8+7
    const int n0 = c * 4;                  // quads n0 and n0+256

    float acc[8][8];
#pragma unroll
    for (int r = 0; r < 8; ++r)
#pragma unroll
        for (int j = 0; j < 8; ++j) acc[r][j] = 0.f;

    for (int k0 = 0; k0 < K2; k0 += 16) {
        __syncthreads();                   // As2 ready / prior Wt reads done
        // stage Wtile[16][512]: 2048 uint4, 8 per thread, coalesced
        {
            const uint4* Wg = (const uint4*)(Wp + (size_t)k0 * 512);
            uint4* Wt4 = (uint4*)Wt;
#pragma unroll
            for (int u = 0; u < 8; ++u) Wt4[t + u * 256] = Wg[t + u * 256];
        }
        __syncthreads();

#pragma unroll
        for (int kk = 0; kk < 16; kk += 2) {
            uint4 wA0 = *(const uint4*)(Wt + kk * 512 + n0);
            uint4 wB0 = *(const uint4*)(Wt + kk * 512 + n0 + 256);
            uint4 wA1 = *(const uint4*)(Wt + (kk + 1) * 512 + n0);
            uint4 wB1 = *(const uint4*)(Wt + (kk + 1) * 512 + n0 + 256);
#pragma unroll
            for (int r = 0; r < 8; ++r) {
                uint2 a = *(const uint2*)(As2 + (size_t)(rg * 8 + r) * K2 + k0 + kk);
                dot8(acc[r], a.x, wA0, wB0);
                dot8(acc[r], a.y, wA1, wB1);
            }
        }
    }

    float bv[8];
#pragma unroll
    for (int j = 0; j < 4; ++j) { bv[j] = bias[n0 + j]; bv[4 + j] = bias[n0 + 256 + j]; }

#pragma unroll
    for (int r = 0; r < 8; ++r) {
        float* Crow = C + (size_t)(m0 + rg * 8 + r) * 512;
        *(float4*)(Crow + n0)       = make_float4(acc[r][0] + bv[0], acc[r][1] + bv[1],
                                                  acc[r][2] + bv[2], acc[r][3] + bv[3]);
        *(float4*)(Crow + n0 + 256) = make_float4(acc[r][4] + bv[4], acc[r][5] + bv[5],
                                                  acc[r][6] + bv[6], acc[r][7] + bv[7]);
    }
}

// ---------------------------------------------------------------------------
// RNN scan: ONE CU per batch, full K per thread, weights pinned on-chip.
// Thread i = row i: 228 f16x2 pairs in VGPRs (57 uint4, laundered through an
// empty asm so the allocator cannot rematerialize the loads) + 28 pairs in
// LDS (pair-major Wlds[7][512] -> consecutive-lane ds_read_b128).  h repack:
// store h as f16 to LDS, reload as packed u32 pairs (no pack ALU).  No
// cross-CU traffic at all.  8 waves x 256 VGPR = full register file.
// ---------------------------------------------------------------------------
#define NVQ 57   // uint4 weights in VGPRs (pairs 0..227)
#define NLQ 7    // uint4 weights in LDS  (pairs 228..255)

__launch_bounds__(512, 2)
__global__ void rnn_scan4(const unsigned* __restrict__ Wq,   // [512][256] f16x2
                          const float* __restrict__ h0,      // [B][512]
                          float* __restrict__ states,        // [T][B][512] in:pre out:h
                          float* __restrict__ last) {        // [B][512]
    __shared__ uint4 Wlds[NLQ][HH];            // 57344 B
    __shared__ unsigned short hsh[2][HH];      // 2048 B

    const int b = blockIdx.x;
    const int r = threadIdx.x;                 // my row
    const int lane = r & 63;

    // cooperative LDS weight fill (pair-major)
    for (int idx = r; idx < NLQ * HH; idx += 512) {
        int q = idx >> 9, row = idx & 511;
        Wlds[q][row] = ((const uint4*)(Wq + (size_t)row * 256))[NVQ + q];
    }

    // VGPR weights, laundered so they MUST stay in registers
    uint4 wreg[NVQ];
    {
        const uint4* Wr = (const uint4*)(Wq + (size_t)r * 256);
#pragma unroll
        for (int q = 0; q < NVQ; ++q) {
            uint4 v = Wr[q];
            asm volatile("" : "+v"(v.x), "+v"(v.y), "+v"(v.z), "+v"(v.w));
            wreg[q] = v;
        }
    }

    // initial hp: all 256 h-pairs replicated per wave
    unsigned hp[4];
    {
        const float2* h02 = (const float2*)(h0 + (size_t)b * HH);
#pragma unroll
        for (int rr = 0; rr < 4; ++rr) {
            float2 v = h02[rr * 64 + lane];
            hp[rr] = pack_f16x2(v.x, v.y);
        }
    }
    __syncthreads();                           // Wlds ready

    const size_t tstride = (size_t)BB * HH;
    const float* sp = states + (size_t)b * HH + r;
    float* spw = states + (size_t)b * HH + r;
    float pre_cur = *sp;
    float h = 0.f;

    for (int t = 0; t < TT; ++t) {
        // prefetch next pre (address valid even at t=TT-1: lands in last[] region)
        float pre_nxt = sp[tstride];

        float a0 = 0.f, a1 = 0.f, a2 = 0.f, a3 = 0.f;
#pragma unroll
        for (int q = 0; q < NVQ; ++q) {
            const uint4 wv = wreg[q];
            const int j = q * 4;
            unsigned s0 = (unsigned)__builtin_amdgcn_readlane((int)hp[(j + 0) >> 6], (j + 0) & 63);
            unsigned s1 = (unsigned)__builtin_amdgcn_readlane((int)hp[(j + 1) >> 6], (j + 1) & 63);
            unsigned s2 = (unsigned)__builtin_amdgcn_readlane((int)hp[(j + 2) >> 6], (j + 2) & 63);
            unsigned s3 = (unsigned)__builtin_amdgcn_readlane((int)hp[(j + 3) >> 6], (j + 3) & 63);
            a0 = fdot2(wv.x, s0, a0);
            a1 = fdot2(wv.y, s1, a1);
            a2 = fdot2(wv.z, s2, a2);
            a3 = fdot2(wv.w, s3, a3);
        }
#pragma unroll
        for (int q = 0; q < NLQ; ++q) {
            const uint4 wv = Wlds[q][r];
            const int j = (NVQ + q) * 4;
            unsigned s0 = (unsigned)__builtin_amdgcn_readlane((int)hp[(j + 0) >> 6], (j + 0) & 63);
            unsigned s1 = (unsigned)__builtin_amdgcn_readlane((int)hp[(j + 1) >> 6], (j + 1) & 63);
            unsigned s2 = (unsigned)__builtin_amdgcn_readlane((int)hp[(j + 2) >> 6], (j + 2) & 63);
            unsigned s3 = (unsigned)__builtin_amdgcn_readlane((int)hp[(j + 3) >> 6], (j + 3) & 63);
            a0 = fdot2(wv.x, s0, a0);
            a1 = fdot2(wv.y, s1, a1);
            a2 = fdot2(wv.z, s2, a2);
            a3 = fdot2(wv.w, s3, a3);
        }
        float part = (a0 + a1) + (a2 + a3);

        h = tanh_fast(pre_cur + part);
        *spw = h;

        const int p = t & 1;
        hsh[p][r] = (unsigned short)__half_as_ushort(__float2half_rn(h));
        __syncthreads();
        const unsigned* hh32 = (const unsigned*)&hsh[p][0];
#pragma unroll
        for (int rr = 0; rr < 4; ++rr) hp[rr] = hh32[rr * 64 + lane];

        pre_cur = pre_nxt;
        sp  += tstride;
        spw += tstride;
    }

    last[(size_t)b * HH + r] = h;
}

// ---------------------------------------------------------------------------
extern "C" void kernel_launch(void* const* d_in, const int* in_sizes, int n_in,
                              void* d_out, int out_size, void* d_ws, size_t ws_size,
                              hipStream_t stream) {
    (void)in_sizes; (void)n_in; (void)out_size; (void)ws_size;
    const float* inputs = (const float*)d_in[0];   // (T,B,V)
    const float* H      = (const float*)d_in[1];   // (L,B,HID)
    const float* Wnet   = (const float*)d_in[2];   // (HID, V+HID)
    const float* bnet   = (const float*)d_in[3];   // (HID,)
    const float* Wdeep  = (const float*)d_in[4];   // (HID, 2*HID)
    const float* bdeep  = (const float*)d_in[5];   // (HID,)
    float* out = (float*)d_out;

    // workspace layout (~1.75 MB)
    unsigned* Wq0 = (unsigned*)d_ws;               // 131072 u32
    unsigned* Wq1 = Wq0 + HH * (HH / 2);           // 131072 u32
    unsigned* Wp0 = Wq1 + HH * (HH / 2);           // 65536 u32
    unsigned* Wp1 = Wp0 + (VV / 2) * HH;           // 131072 u32

    // 1) pack weights
    hipLaunchKernelGGL(pack_weights, dim3(1792), dim3(256), 0, stream,
                       Wnet, Wdeep, Wq0, Wq1, Wp0, Wp1);

    // 2) pre0 = inputs @ Wx0^T + b_net  -> d_out[0:TBH]   (K2 = 128)
    hipLaunchKernelGGL(xproj_f16, dim3((TT * BB) / 32), dim3(256),
                       (32 * (VV / 2) + 16 * 512) * sizeof(unsigned), stream,
                       inputs, Wp0, bnet, out, VV / 2);

    // 3) layer-0 scan
    hipLaunchKernelGGL(rnn_scan4, dim3(BB), dim3(512), 0, stream,
                       Wq0, H, out, out + TBH);

    // 4) pre1 = states0 @ Wx1^T + b_deep (in-place)       (K2 = 256)
    hipLaunchKernelGGL(xproj_f16, dim3((TT * BB) / 32), dim3(256),
                       (32 * (HH / 2) + 16 * 512) * sizeof(unsigned), stream,
                       out, Wp1, bdeep, out, HH / 2);

    // 5) layer-1 scan
    hipLaunchKernelGGL(rnn_scan4, dim3(BB), dim3(512), 0, stream,
                       Wq1, H + (size_t)BB * HH, out, out + TBH + (size_t)BB * HH);
}